// Round 3
// baseline (357.929 us; speedup 1.0000x reference)
//
#include <hip/hip_runtime.h>

// cReLU_percent: x (32,128,112,112) fp32. Per pixel (n,h,w): keep channel
// values >= the 64th-largest across C=128, then ReLU; zero the rest.
//
// R4: 4 lanes per pixel, 32 channels each (was 2x64). Each lane bitonic-sorts
// 32 values (240 CEs vs 672), lane pairs (xor 1) bitonic-merge into sorted-64
// (32 shfl + 32 CE + 5-stage clean), then the threshold comes from the
// bitonic-split identity across xor-3 partners: thr = min_i max(M01[i],
// M23[63-i]). Live state is 32 sort regs -> VGPR <= 64 -> 8 waves/SIMD
// (R3 was 68 VGPR = 4 waves/SIMD, 28% occupancy, 3.0 TB/s: latency-bound).
// __launch_bounds__(256,8) pins the allocator under the cliff.
// PBLK=64 so the epilogue is exactly 8 float4/thread; those loads are issued
// BEFORE __syncthreads so their latency hides under the barrier. nt stores
// keep write-only `out` from evicting `x`.
//
// (R4 resubmit: previous round died to "MI355X container failed twice" —
// infra flake, no counters. Kernel re-audited: no OOB, no divergent barrier,
// merge/threshold identities re-derived. Unchanged.)

#define CC        128
#define HWSZ      12544     // 112*112
#define PBLK      64        // pixels per block (12544 = 196 * 64)
#define NBLK_PER_N 196

using f32x4 = __attribute__((ext_vector_type(4))) float;

__device__ __forceinline__ void sort32(float v[32]) {
  // full bitonic sort, ascending
  #pragma unroll
  for (int k = 2; k <= 32; k <<= 1) {
    #pragma unroll
    for (int j = k >> 1; j > 0; j >>= 1) {
      #pragma unroll
      for (int i = 0; i < 32; ++i) {
        int l = i ^ j;
        if (l > i) {
          float lo = fminf(v[i], v[l]);
          float hi = fmaxf(v[i], v[l]);
          bool up = ((i & k) == 0);   // compile-time after unroll
          v[i] = up ? lo : hi;
          v[l] = up ? hi : lo;
        }
      }
    }
  }
}

__device__ __forceinline__ void clean32(float v[32]) {
  // bitonic merge: input bitonic sequence -> ascending sorted
  #pragma unroll
  for (int j = 16; j > 0; j >>= 1) {
    #pragma unroll
    for (int i = 0; i < 32; ++i) {
      int l = i ^ j;
      if (l > i) {
        float lo = fminf(v[i], v[l]);
        float hi = fmaxf(v[i], v[l]);
        v[i] = lo;
        v[l] = hi;
      }
    }
  }
}

__global__ __launch_bounds__(256, 8) void crelu_pct_kernel(
    const float* __restrict__ x, float* __restrict__ out) {
  __shared__ __align__(16) float thr_lds[PBLK];

  const int tid = threadIdx.x;
  const int n   = blockIdx.x / NBLK_PER_N;
  const int pb  = (blockIdx.x - n * NBLK_PER_N) * PBLK;
  const size_t planeN = (size_t)CC * HWSZ;

  // ---- phase A: lane quad (4 lanes per pixel) sorts 32 channels each ----
  const int q   = tid >> 2;         // local pixel 0..63
  const int grp = tid & 3;          // channel group: grp*32 .. grp*32+31
  const float* xp = x + (size_t)n * planeN
                      + (size_t)(grp << 5) * HWSZ
                      + (size_t)(pb + q);

  float v[32];
  #pragma unroll
  for (int c = 0; c < 32; ++c) v[c] = xp[(size_t)c * HWSZ];
  sort32(v);                        // ascending

  // ---- phase B1: bitonic merge across xor-1 partner -> sorted 64 per pair
  // lower lane (even grp) keeps min(A[i], B[31-i]); upper keeps the maxes
  // (reversed bitonic), each cleans locally -> (grp0 asc ++ grp1 asc) sorted.
  {
    const bool upper = (grp & 1);
    #pragma unroll
    for (int i = 0; i < 16; ++i) {
      const int ir = 31 - i;
      float oa = __shfl_xor(v[ir], 1, 64);   // partner's v[31-i] for my v[i]
      float ob = __shfl_xor(v[i],  1, 64);   // partner's v[i]    for my v[ir]
      float loa = fminf(v[i],  oa), hia = fmaxf(v[i],  oa);
      float lob = fminf(v[ir], ob), hib = fmaxf(v[ir], ob);
      v[i]  = upper ? hia : loa;
      v[ir] = upper ? hib : lob;
    }
    clean32(v);
  }

  // ---- phase B2: thr = min_i max(M01[i], M23[63-i]) across xor-3 partners
  float thr = 3.4e38f;
  {
    #pragma unroll
    for (int i = 0; i < 16; ++i) {
      const int ir = 31 - i;
      float oa = __shfl_xor(v[ir], 3, 64);
      float ob = __shfl_xor(v[i],  3, 64);
      thr = fminf(thr, fmaxf(v[i],  oa));
      thr = fminf(thr, fmaxf(v[ir], ob));
    }
    thr = fminf(thr, __shfl_xor(thr, 1, 64));
    thr = fminf(thr, __shfl_xor(thr, 2, 64));
  }
  if (grp == 0) thr_lds[q] = thr;

  // ---- phase D: pixel-major float4 re-read (issued pre-barrier) ----
  // thread -> fixed pixel-quad j (pixels pb+4j..4j+3), channels c0+16i.
  const int j  = tid & 15;
  const int c0 = tid >> 4;          // 0..15
  const size_t rowpix = (size_t)n * planeN + (size_t)pb + (size_t)(j << 2);

  f32x4 w[8];
  #pragma unroll
  for (int i = 0; i < 8; ++i) {
    const int c = (i << 4) + c0;
    w[i] = *reinterpret_cast<const f32x4*>(x + rowpix + (size_t)c * HWSZ);
  }

  __syncthreads();
  const f32x4 t4 = *reinterpret_cast<const f32x4*>(&thr_lds[j << 2]);

  #pragma unroll
  for (int i = 0; i < 8; ++i) {
    const int c = (i << 4) + c0;
    f32x4 r;
    #pragma unroll
    for (int e = 0; e < 4; ++e)
      r[e] = (w[i][e] >= t4[e] && w[i][e] > 0.0f) ? w[i][e] : 0.0f;
    __builtin_nontemporal_store(
        r, reinterpret_cast<f32x4*>(out + rowpix + (size_t)c * HWSZ));
  }
}

extern "C" void kernel_launch(void* const* d_in, const int* in_sizes, int n_in,
                              void* d_out, int out_size, void* d_ws, size_t ws_size,
                              hipStream_t stream) {
  const float* x = (const float*)d_in[0];
  float* out = (float*)d_out;
  const int npix = in_sizes[0] / CC;     // 401408
  const int grid = npix / PBLK;          // 6272 exactly
  crelu_pct_kernel<<<grid, 256, 0, stream>>>(x, out);
}

// Round 4
// 356.550 us; speedup vs baseline: 1.0039x; 1.0039x over previous
//
#include <hip/hip_runtime.h>

// cReLU_percent: x (32,128,112,112) fp32. Per pixel (n,h,w): keep channel
// values >= the 64th-largest across C=128, then ReLU; zero the rest.
//
// R5: same 4-lanes-per-pixel bitonic threshold network as R4 (sort32 +
// xor-1 bitonic merge + xor-3 bitonic-split threshold), but 4x the pixel
// footprint per block: PBLK=256, block=1024 threads (16 waves).
// Why: R2/R3/R4 all pinned at ~130us regardless of occupancy (18/28/70%)
// with HBM at 2.5-3.0 TB/s — DRAM-efficiency-bound, not latency-bound.
// Per block each channel-plane was touched in a 256 B island at 50 KB
// channel stride -> poor row-buffer locality. Now:
//  - phase D: c0=tid>>6 is wave-uniform, j=lane -> every float4 load/store
//    instruction covers 64 lanes x 16 B = 1 KB CONTIGUOUS (was 4x256B).
//  - phase A: block covers 1 KB per channel-plane, 16 co-resident waves
//    cluster the requests.
// __launch_bounds__(1024,8): <=64 VGPR (R4 compiled at 28), 2 blocks/CU.
// nt stores keep write-only `out` from evicting x (205 MB fits 256 MB L3).

#define CC        128
#define HWSZ      12544     // 112*112
#define PBLK      256       // pixels per block (12544 = 49 * 256)
#define NBLK_PER_N 49

using f32x4 = __attribute__((ext_vector_type(4))) float;

__device__ __forceinline__ void sort32(float v[32]) {
  // full bitonic sort, ascending
  #pragma unroll
  for (int k = 2; k <= 32; k <<= 1) {
    #pragma unroll
    for (int j = k >> 1; j > 0; j >>= 1) {
      #pragma unroll
      for (int i = 0; i < 32; ++i) {
        int l = i ^ j;
        if (l > i) {
          float lo = fminf(v[i], v[l]);
          float hi = fmaxf(v[i], v[l]);
          bool up = ((i & k) == 0);   // compile-time after unroll
          v[i] = up ? lo : hi;
          v[l] = up ? hi : lo;
        }
      }
    }
  }
}

__device__ __forceinline__ void clean32(float v[32]) {
  // bitonic merge: input bitonic sequence -> ascending sorted
  #pragma unroll
  for (int j = 16; j > 0; j >>= 1) {
    #pragma unroll
    for (int i = 0; i < 32; ++i) {
      int l = i ^ j;
      if (l > i) {
        float lo = fminf(v[i], v[l]);
        float hi = fmaxf(v[i], v[l]);
        v[i] = lo;
        v[l] = hi;
      }
    }
  }
}

__global__ __launch_bounds__(1024, 8) void crelu_pct_kernel(
    const float* __restrict__ x, float* __restrict__ out) {
  __shared__ __align__(16) float thr_lds[PBLK];

  const int tid = threadIdx.x;
  const int n   = blockIdx.x / NBLK_PER_N;
  const int pb  = (blockIdx.x - n * NBLK_PER_N) * PBLK;
  const size_t planeN = (size_t)CC * HWSZ;

  // ---- phase A: lane quad (4 lanes per pixel) sorts 32 channels each ----
  const int q   = tid >> 2;         // local pixel 0..255
  const int grp = tid & 3;          // channel group: grp*32 .. grp*32+31
  const float* xp = x + (size_t)n * planeN
                      + (size_t)(grp << 5) * HWSZ
                      + (size_t)(pb + q);

  float v[32];
  #pragma unroll
  for (int c = 0; c < 32; ++c) v[c] = xp[(size_t)c * HWSZ];
  sort32(v);                        // ascending

  // ---- phase B1: bitonic merge across xor-1 partner -> sorted 64 per pair
  // lower lane (even grp) keeps min(A[i], B[31-i]); upper keeps the maxes
  // (reversed bitonic), each cleans locally -> (grp0 asc ++ grp1 asc) sorted.
  {
    const bool upper = (grp & 1);
    #pragma unroll
    for (int i = 0; i < 16; ++i) {
      const int ir = 31 - i;
      float oa = __shfl_xor(v[ir], 1, 64);   // partner's v[31-i] for my v[i]
      float ob = __shfl_xor(v[i],  1, 64);   // partner's v[i]    for my v[ir]
      float loa = fminf(v[i],  oa), hia = fmaxf(v[i],  oa);
      float lob = fminf(v[ir], ob), hib = fmaxf(v[ir], ob);
      v[i]  = upper ? hia : loa;
      v[ir] = upper ? hib : lob;
    }
    clean32(v);
  }

  // ---- phase B2: thr = min_i max(M01[i], M23[63-i]) across xor-3 partners
  float thr = 3.4e38f;
  {
    #pragma unroll
    for (int i = 0; i < 16; ++i) {
      const int ir = 31 - i;
      float oa = __shfl_xor(v[ir], 3, 64);
      float ob = __shfl_xor(v[i],  3, 64);
      thr = fminf(thr, fmaxf(v[i],  oa));
      thr = fminf(thr, fmaxf(v[ir], ob));
    }
    thr = fminf(thr, __shfl_xor(thr, 1, 64));
    thr = fminf(thr, __shfl_xor(thr, 2, 64));
  }
  if (grp == 0) thr_lds[q] = thr;

  // ---- phase D: wave-contiguous float4 re-read (issued pre-barrier) ----
  // wave w owns channels {w + 16i}; lane j owns pixel-quad 4j..4j+3.
  // Each load/store instruction: 64 lanes x 16 B = 1 KB contiguous.
  const int j  = tid & 63;          // lane within wave
  const int c0 = tid >> 6;          // wave index 0..15 (uniform per wave)
  const size_t rowpix = (size_t)n * planeN + (size_t)pb + (size_t)(j << 2);

  f32x4 w[8];
  #pragma unroll
  for (int i = 0; i < 8; ++i) {
    const int c = (i << 4) + c0;
    w[i] = *reinterpret_cast<const f32x4*>(x + rowpix + (size_t)c * HWSZ);
  }

  __syncthreads();
  const f32x4 t4 = *reinterpret_cast<const f32x4*>(&thr_lds[j << 2]);

  #pragma unroll
  for (int i = 0; i < 8; ++i) {
    const int c = (i << 4) + c0;
    f32x4 r;
    #pragma unroll
    for (int e = 0; e < 4; ++e)
      r[e] = (w[i][e] >= t4[e] && w[i][e] > 0.0f) ? w[i][e] : 0.0f;
    __builtin_nontemporal_store(
        r, reinterpret_cast<f32x4*>(out + rowpix + (size_t)c * HWSZ));
  }
}

extern "C" void kernel_launch(void* const* d_in, const int* in_sizes, int n_in,
                              void* d_out, int out_size, void* d_ws, size_t ws_size,
                              hipStream_t stream) {
  const float* x = (const float*)d_in[0];
  float* out = (float*)d_out;
  const int npix = in_sizes[0] / CC;     // 401408
  const int grid = npix / PBLK;          // 1568 exactly
  crelu_pct_kernel<<<grid, 1024, 0, stream>>>(x, out);
}